// Round 6
// baseline (163.001 us; speedup 1.0000x reference)
//
#include <hip/hip_runtime.h>
#include <hip/hip_bf16.h>

// Problem constants (B=2, S=2048, E=1024, H=16, Dh=64)
#define S_LEN 2048
#define EMB   1024
#define NH    16
#define DH    64
#define QKV_LD 3072   // 3*EMB

typedef __attribute__((ext_vector_type(8)))  __bf16 bf16x8;
typedef __attribute__((ext_vector_type(4)))  __bf16 bf16x4;
typedef __attribute__((ext_vector_type(4)))  float  f32x4;
typedef __attribute__((ext_vector_type(16))) float  f32x16;
typedef __attribute__((ext_vector_type(2)))  unsigned int u32x2;

// ---- async global->LDS (16B per lane; LDS dst = wave-uniform base) ----
__device__ __forceinline__ void gl_lds16(const void* g, void* l) {
  __builtin_amdgcn_global_load_lds(
      (const __attribute__((address_space(1))) void*)g,
      (__attribute__((address_space(3))) void*)l,
      16, 0, 0);
}

// ---------------- fused prep: cast x -> bf16, transpose+cast both weights --
__global__ __launch_bounds__(256)
void prep_fused(const float* __restrict__ x, __bf16* __restrict__ xb,
                const float* __restrict__ w_attn, __bf16* __restrict__ wat,
                const float* __restrict__ w_proj, __bf16* __restrict__ wpt,
                int n8) {
  __shared__ float T[64][65];
  const int bid = blockIdx.x;
  const int tid = threadIdx.x;

  if (bid < 2048) {
    int i = bid * 256 + tid;
    if (i >= n8) return;
    const f32x4* p = (const f32x4*)(x + (size_t)i * 8);
    f32x4 a = p[0], b = p[1];
    bf16x8 o;
    #pragma unroll
    for (int j = 0; j < 4; j++) { o[j] = (__bf16)a[j]; o[4 + j] = (__bf16)b[j]; }
    *(bf16x8*)(xb + (size_t)i * 8) = o;
    return;
  }

  const float* W; __bf16* Wt; int K, N, k0, n0;
  if (bid < 2048 + 768) {
    int t = bid - 2048;                 // w_attn: N=3072 -> 48 x-tiles, 16 k-tiles
    W = w_attn; Wt = wat; K = 1024; N = 3072;
    n0 = (t % 48) * 64; k0 = (t / 48) * 64;
  } else {
    int t = bid - 2816;                 // w_proj: 16 x 16 tiles
    W = w_proj; Wt = wpt; K = 1024; N = 1024;
    n0 = (t & 15) * 64; k0 = (t >> 4) * 64;
  }
  #pragma unroll
  for (int t = 0; t < 16; t++) {
    int idx = tid + t * 256;
    int r = idx >> 6, c = idx & 63;
    T[r][c] = W[(size_t)(k0 + r) * N + n0 + c];
  }
  __syncthreads();
  #pragma unroll
  for (int t = 0; t < 16; t++) {
    int idx = tid + t * 256;
    int r = idx >> 6, c = idx & 63;     // r = local n, c = local k
    Wt[(size_t)(n0 + r) * K + k0 + c] = (__bf16)T[c][r];
  }
}

// ---------------- bf16 MFMA GEMM: C(MxN) = A(MxK) @ Bt(NxK)^T -------------
#define TM 128
#define TK 32

template <typename OutT, int TNv>
__global__ __launch_bounds__(256, 2)
void gemm_bf16_mfma(const __bf16* __restrict__ A, const __bf16* __restrict__ Bt,
                    OutT* __restrict__ C, int M, int N, int K) {
  __shared__ __align__(16) __bf16 As[2][TM][TK];
  __shared__ __align__(16) __bf16 Bs[2][TNv][TK];
  const int tid  = threadIdx.x;
  const int lane = tid & 63;
  const int w    = tid >> 6;
  const int wr   = w >> 1, wc = w & 1;
  const int brow = blockIdx.y * TM;
  const int bcol = blockIdx.x * TNv;
  const int l15  = lane & 15;
  const int grp  = lane >> 4;

  constexpr int NBI = TNv / 64;        // B staging issues per wave
  constexpr int WCT = TNv / 2;         // wave column tile
  constexpr int NN  = WCT / 16;        // n-fragments per wave

  auto stage = [&](int k0, int buf) {
    #pragma unroll
    for (int j = 0; j < 2; j++) {       // A: 128x32 = 512 chunks, 2/wave
      const int cid = w * 128 + j * 64 + lane;
      const int row = cid >> 2, k8 = (cid & 3) * 8;
      gl_lds16(A + (size_t)(brow + row) * K + k0 + k8,
               &As[buf][0][0] + (size_t)(w * 128 + j * 64) * 8);
    }
    #pragma unroll
    for (int j = 0; j < NBI; j++) {     // B: TNv x 32 chunks
      const int cid = (w * NBI + j) * 64 + lane;
      const int row = cid >> 2, k8 = (cid & 3) * 8;
      gl_lds16(Bt + (size_t)(bcol + row) * K + k0 + k8,
               &Bs[buf][0][0] + (size_t)((w * NBI + j) * 64) * 8);
    }
  };

  f32x4 acc[4][NN];
  #pragma unroll
  for (int m = 0; m < 4; m++)
    #pragma unroll
    for (int n = 0; n < NN; n++) acc[m][n] = (f32x4){0.f, 0.f, 0.f, 0.f};

  stage(0, 0);
  __syncthreads();                      // drains prologue vmcnt

  const int nk = K / TK;
  for (int kt = 0; kt < nk; kt++) {
    const int cur = kt & 1;
    if (kt + 1 < nk) stage((kt + 1) * TK, cur ^ 1);   // prefetch under MFMA

    bf16x8 a[4], b[NN];
    #pragma unroll
    for (int m = 0; m < 4; m++)
      a[m] = *(const bf16x8*)&As[cur][wr * 64 + m * 16 + l15][grp * 8];
    #pragma unroll
    for (int n = 0; n < NN; n++)
      b[n] = *(const bf16x8*)&Bs[cur][wc * WCT + n * 16 + l15][grp * 8];
    #pragma unroll
    for (int m = 0; m < 4; m++)
      #pragma unroll
      for (int n = 0; n < NN; n++)
        acc[m][n] = __builtin_amdgcn_mfma_f32_16x16x32_bf16(a[m], b[n], acc[m][n], 0, 0, 0);

    __syncthreads();   // all waves done reading cur; prefetch landed
  }

  #pragma unroll
  for (int m = 0; m < 4; m++)
    #pragma unroll
    for (int r = 0; r < 4; r++) {
      const size_t row = (size_t)(brow + wr * 64 + m * 16 + grp * 4 + r);
      #pragma unroll
      for (int n = 0; n < NN; n++)
        C[row * N + bcol + wc * WCT + n * 16 + l15] = (OutT)acc[m][n][r];
    }
}

// ---------------- MFMA flash attention v19: KB=128 fat iterations ---------
// R0-R5 synthesis: per-iteration cost ~1500 CU-cyc is fixed overhead
// (X-wait, 3 barriers, reductions) regardless of chain count/occupancy;
// 66 iters/CU at KB=64 = 41us.  v19 doubles the K-tile to 128 keys: same
// overhead amortized over 2x work, 34 iters/CU.  No split-K, no merge
// kernel (write amplification + merge cost gone); v13's zigzag+XCD block
// distribution (1024 blocks, qtile iters balanced pairwise).
// Engine: v17's 3-barrier single-buffer schedule.  K = [128][64] bf16
// row-swizzled (16 KB); V = two 8 KB sub-buffers (key halves), each in the
// verified v10 law; wave kh owns sub-buffer kh, its two 32-key MFMA chunks
// select +0/+1024 inside (was kh*1024 at KB=64).  LDS 33 KB -> 4 blocks/CU.
#define QB 64
#define KB 128
#define QSCALE 0.18033688f   // 0.125 * log2(e)

__global__ __launch_bounds__(256, 4)
void attn_mfma(const __bf16* __restrict__ qkv, __bf16* __restrict__ y) {
  // 33792 B: Ks [128][64] bf16 (16KB) | Vs 2x8KB (16KB) | exML 1KB
  __shared__ __align__(16) char SMEM[33792];

  const int tid  = threadIdx.x;
  const int lane = tid & 63;
  const int w    = tid >> 6;

  // XCD-grouping swizzle + zigzag work balance (v13's decode, 1024 blocks)
  const int bid = blockIdx.x;                 // 0..1023
  const int swz = (bid & 7) * 128 + (bid >> 3);
  const int g   = swz >> 5;                   // (b,h) group 0..31
  const int i   = swz & 31;
  const int zig = (i & 1) ? (i >> 1) : 31 - (i >> 1);
  const int qtile = (g & 1) ? 31 - zig : zig;
  const int h = g & 15, b = g >> 4;

  const __bf16* base = qkv + (size_t)b * S_LEN * QKV_LD;

  const int l31 = lane & 31;
  const int hl  = lane >> 5;          // lane half (0/1)
  const int qh  = w >> 1;             // q-half of the 64-row tile
  const int kh  = w & 1;              // key-half (64 keys each) of the 128-tile

  // tr_read per-lane base inside wave's V sub-buffer (chunk bit in offsets)
  const int voff32 = ((lane >> 4) & 1) * 2048 + hl * 128 + (lane & 15) * 8;

  auto stageK = [&](int j0) {
    #pragma unroll
    for (int jj = 0; jj < 4; jj++) {
      const int cid = w * 256 + jj * 64 + lane;    // chunk 0..1023
      const int r = cid >> 3, pc = cid & 7;        // r = key row 0..127
      const int lc = pc ^ (r & 7);                 // inverse swizzle on source
      gl_lds16(base + (size_t)(j0 + r) * QKV_LD + EMB + h * DH + lc * 8,
               SMEM + cid * 16);
    }
  };
  auto stageV = [&](int j0) {
    #pragma unroll
    for (int jj = 0; jj < 4; jj++) {
      const int cid = w * 256 + jj * 64 + lane;    // chunk 0..1023
      const int c  = cid >> 9;                     // key-half sub-buffer
      const int cc = cid & 511;                    // old 8KB law inside
      const int db = cc >> 7, sk = (cc >> 3) & 15;
      const int jr = (cc >> 1) & 3, ch = cc & 1;
      gl_lds16(base + (size_t)(j0 + c * 64 + sk * 4 + jr) * QKV_LD + 2 * EMB
                    + h * DH + db * 16 + ch * 8,
               SMEM + 16384 + cid * 16);
    }
  };

  const int qbase = qtile * QB;
  const int q = qbase + qh * 32 + l31;           // this lane's q row

  // Q B-fragments (col=q, k_hw=d): qf[dq][i] = Q[q][dq*16 + hl*8 + i]
  bf16x8 qf[4];
  {
    const __bf16* qp = base + (size_t)q * QKV_LD + h * DH;
    #pragma unroll
    for (int dq = 0; dq < 4; dq++) {
      bf16x8 v = *(const bf16x8*)(qp + dq * 16 + hl * 8);
      #pragma unroll
      for (int i2 = 0; i2 < 8; i2++) qf[dq][i2] = (__bf16)((float)v[i2] * QSCALE);
    }
  }

  f32x16 o_acc[2];
  #pragma unroll
  for (int d2 = 0; d2 < 2; d2++)
    #pragma unroll
    for (int r = 0; r < 16; r++) o_acc[d2][r] = 0.f;
  float m = -1e30f, l = 0.f;

  const int krow0 = kh * 64 + l31;     // chunk 0 K-row; chunk 1 = +32
  const int ksw   = l31 & 7;           // swizzle key (same for both chunks)

  auto iter = [&](int j0, bool masked, int jn, bool do_stage) {
    asm volatile("s_waitcnt vmcnt(0)" ::: "memory");
    __builtin_amdgcn_s_barrier();                      // X: K,V of tile landed
    __builtin_amdgcn_sched_barrier(0);

    // ---- S^T = K Q: two 32k x 32q chunks, chained over d ----
    f32x16 s0, s1;
    #pragma unroll
    for (int r = 0; r < 16; r++) { s0[r] = 0.f; s1[r] = 0.f; }
    __builtin_amdgcn_s_setprio(1);
    #pragma unroll
    for (int dq = 0; dq < 4; dq++) {
      const int col = ((dq * 2 + hl) ^ ksw) * 16;
      bf16x8 kf0 = *(const bf16x8*)(SMEM + krow0 * 128 + col);
      bf16x8 kf1 = *(const bf16x8*)(SMEM + (krow0 + 32) * 128 + col);
      s0 = __builtin_amdgcn_mfma_f32_32x32x16_bf16(kf0, qf[dq], s0, 0, 0, 0);
      s1 = __builtin_amdgcn_mfma_f32_32x32x16_bf16(kf1, qf[dq], s1, 0, 0, 0);
    }
    __builtin_amdgcn_s_setprio(0);

    if (masked) {
      const int lim0 = q - j0 - kh * 64 - 4 * hl;  // keep if kl <= lim
      #pragma unroll
      for (int r = 0; r < 16; r++) {
        const int kl = (r & 3) + 8 * (r >> 2);
        if (kl > lim0)      s0[r] = -2e30f;
        if (kl > lim0 - 32) s1[r] = -2e30f;
      }
    }

    // ---- issue all 16 V^T transpose reads (latency under max tree) ----
    const unsigned vb =
        (unsigned)(uintptr_t)(__attribute__((address_space(3))) char*)
            (SMEM + 16384) + (unsigned)(kh * 8192 + voff32);
    u32x2 tv0[8], tv1[8];
    asm volatile("ds_read_b64_tr_b16 %0, %1 offset:0"    : "=v"(tv0[0]) : "v"(vb));
    asm volatile("ds_read_b64_tr_b16 %0, %1 offset:256"  : "=v"(tv0[1]) : "v"(vb));
    asm volatile("ds_read_b64_tr_b16 %0, %1 offset:512"  : "=v"(tv0[2]) : "v"(vb));
    asm volatile("ds_read_b64_tr_b16 %0, %1 offset:768"  : "=v"(tv0[3]) : "v"(vb));
    asm volatile("ds_read_b64_tr_b16 %0, %1 offset:4096" : "=v"(tv0[4]) : "v"(vb));
    asm volatile("ds_read_b64_tr_b16 %0, %1 offset:4352" : "=v"(tv0[5]) : "v"(vb));
    asm volatile("ds_read_b64_tr_b16 %0, %1 offset:4608" : "=v"(tv0[6]) : "v"(vb));
    asm volatile("ds_read_b64_tr_b16 %0, %1 offset:4864" : "=v"(tv0[7]) : "v"(vb));
    asm volatile("ds_read_b64_tr_b16 %0, %1 offset:1024" : "=v"(tv1[0]) : "v"(vb));
    asm volatile("ds_read_b64_tr_b16 %0, %1 offset:1280" : "=v"(tv1[1]) : "v"(vb));
    asm volatile("ds_read_b64_tr_b16 %0, %1 offset:1536" : "=v"(tv1[2]) : "v"(vb));
    asm volatile("ds_read_b64_tr_b16 %0, %1 offset:1792" : "=v"(tv1[3]) : "v"(vb));
    asm volatile("ds_read_b64_tr_b16 %0, %1 offset:5120" : "=v"(tv1[4]) : "v"(vb));
    asm volatile("ds_read_b64_tr_b16 %0, %1 offset:5376" : "=v"(tv1[5]) : "v"(vb));
    asm volatile("ds_read_b64_tr_b16 %0, %1 offset:5632" : "=v"(tv1[6]) : "v"(vb));
    asm volatile("ds_read_b64_tr_b16 %0, %1 offset:5888" : "=v"(tv1[7]) : "v"(vb));

    // ---- max reduce: pairwise + depth-4 tree + ONE cross-half shuffle ----
    float x0 = fmaxf(fmaxf(s0[0], s1[0]),  fmaxf(s0[8],  s1[8]));
    float x1 = fmaxf(fmaxf(s0[1], s1[1]),  fmaxf(s0[9],  s1[9]));
    float x2 = fmaxf(fmaxf(s0[2], s1[2]),  fmaxf(s0[10], s1[10]));
    float x3 = fmaxf(fmaxf(s0[3], s1[3]),  fmaxf(s0[11], s1[11]));
    float x4 = fmaxf(fmaxf(s0[4], s1[4]),  fmaxf(s0[12], s1[12]));
    float x5 = fmaxf(fmaxf(s0[5], s1[5]),  fmaxf(s0[13], s1[13]));
    float x6 = fmaxf(fmaxf(s0[6], s1[6]),  fmaxf(s0[14], s1[14]));
    float x7 = fmaxf(fmaxf(s0[7], s1[7]),  fmaxf(s0[15], s1[15]));
    x0 = fmaxf(x0, x4); x1 = fmaxf(x1, x5);
    x2 = fmaxf(x2, x6); x3 = fmaxf(x3, x7);
    float tmax = fmaxf(fmaxf(x0, x2), fmaxf(x1, x3));
    tmax = fmaxf(tmax, __shfl_xor(tmax, 32));

    const bool grow = !__all(tmax <= m + 8.0f);
    float corr = 1.f;
    if (grow) {
      const float mnew = fmaxf(m, tmax);
      corr = __builtin_amdgcn_exp2f(m - mnew);
      m = mnew;
    }

    __builtin_amdgcn_s_barrier();                      // Z: all QK reads done
    if (do_stage) stageK(jn);                          // Ks dead -> overwrite

    asm volatile("s_waitcnt lgkmcnt(0)" ::: "memory"); // tr data in regs
    __builtin_amdgcn_sched_barrier(0);
    __builtin_amdgcn_s_barrier();                      // Y: all tr reads done
    if (do_stage) stageV(jn);                          // Vs dead -> overwrite

    // ---- chunk 0: exp2 + psum + pack (frees s0 before chunk 1) ----
    float ps0 = 0.f, ps1 = 0.f, ps2 = 0.f, ps3 = 0.f;
    bf16x8 pb00, pb01, pb10, pb11;
    #pragma unroll
    for (int r = 0; r < 16; r += 4) {
      float p0 = __builtin_amdgcn_exp2f(s0[r]     - m);
      float p1 = __builtin_amdgcn_exp2f(s0[r + 1] - m);
      float p2 = __builtin_amdgcn_exp2f(s0[r + 2] - m);
      float p3 = __builtin_amdgcn_exp2f(s0[r + 3] - m);
      ps0 += p0; ps1 += p1; ps2 += p2; ps3 += p3;
      if (r < 8) { pb00[r] = (__bf16)p0; pb00[r+1] = (__bf16)p1;
                   pb00[r+2] = (__bf16)p2; pb00[r+3] = (__bf16)p3; }
      else       { pb01[r-8] = (__bf16)p0; pb01[r-7] = (__bf16)p1;
                   pb01[r-6] = (__bf16)p2; pb01[r-5] = (__bf16)p3; }
    }
    // ---- chunk 1: exp2 + psum + pack ----
    #pragma unroll
    for (int r = 0; r < 16; r += 4) {
      float p0 = __builtin_amdgcn_exp2f(s1[r]     - m);
      float p1 = __builtin_amdgcn_exp2f(s1[r + 1] - m);
      float p2 = __builtin_amdgcn_exp2f(s1[r + 2] - m);
      float p3 = __builtin_amdgcn_exp2f(s1[r + 3] - m);
      ps0 += p0; ps1 += p1; ps2 += p2; ps3 += p3;
      if (r < 8) { pb10[r] = (__bf16)p0; pb10[r+1] = (__bf16)p1;
                   pb10[r+2] = (__bf16)p2; pb10[r+3] = (__bf16)p3; }
      else       { pb11[r-8] = (__bf16)p0; pb11[r-7] = (__bf16)p1;
                   pb11[r-6] = (__bf16)p2; pb11[r-5] = (__bf16)p3; }
    }
    float psum = (ps0 + ps1) + (ps2 + ps3);

    // ---- O-rescale must precede PV ----
    if (grow) {
      #pragma unroll
      for (int d2 = 0; d2 < 2; d2++)
        #pragma unroll
        for (int r = 0; r < 16; r++) o_acc[d2][r] *= corr;
    }

    // ---- 8 back-to-back PV MFMAs (tv already drained) ----
    __builtin_amdgcn_s_setprio(1);
    #pragma unroll
    for (int d2 = 0; d2 < 2; d2++) {
      bf16x8 a0, a1, a2, a3;
      ((u32x2*)&a0)[0] = tv0[d2 * 4 + 0]; ((u32x2*)&a0)[1] = tv0[d2 * 4 + 1];
      ((u32x2*)&a1)[0] = tv0[d2 * 4 + 2]; ((u32x2*)&a1)[1] = tv0[d2 * 4 + 3];
      ((u32x2*)&a2)[0] = tv1[d2 * 4 + 0]; ((u32x2*)&a2)[1] = tv1[d2 * 4 + 1];
      ((u32x2*)&a3)[0] = tv1[d2 * 4 + 2]; ((u32x2*)&a3)[1] = tv1[d2 * 4 + 3];
      o_acc[d2] = __builtin_amdgcn_mfma_f32_32x32x16_bf16(a0, pb00, o_acc[d2], 0, 0, 0);
      o_acc[d2] = __builtin_amdgcn_mfma_f32_32x32x16_bf16(a1, pb01, o_acc[d2], 0, 0, 0);
      o_acc[d2] = __builtin_amdgcn_mfma_f32_32x32x16_bf16(a2, pb10, o_acc[d2], 0, 0, 0);
      o_acc[d2] = __builtin_amdgcn_mfma_f32_32x32x16_bf16(a3, pb11, o_acc[d2], 0, 0, 0);
    }
    __builtin_amdgcn_s_setprio(0);

    // ---- l-update (off the PV critical path) ----
    psum += __shfl_xor(psum, 32);
    l = grow ? (l * corr + psum) : (l + psum);
  };

  // prologue: stage tile 0 (X-barrier of iteration 0 drains it)
  stageK(0);
  stageV(0);

  const int nt = (qtile + 2) >> 1;     // ceil((qtile+1)/2) 128-key tiles
  #pragma unroll 1
  for (int tt = 0; tt < nt; tt++) {
    iter(tt * KB, tt == nt - 1, (tt + 1) * KB, tt + 1 < nt);
  }

  // ---- kh-pair merge through LDS, then epilogue by kh=0 waves ----
  __syncthreads();     // all waves done; reuse SMEM as exchange space
  float* exO  = (float*)SMEM;               // [32 rows][128 slots] = 16 KB
  float* exML = (float*)(SMEM + 32768);     // [2][128] f32 = 1 KB
  const int slot = qh * 64 + lane;
  if (kh) {
    #pragma unroll
    for (int r = 0; r < 16; r++) {
      exO[r * 128 + slot]        = o_acc[0][r];
      exO[(16 + r) * 128 + slot] = o_acc[1][r];
    }
    exML[slot]       = m;
    exML[128 + slot] = l;
  }
  __syncthreads();
  if (!kh) {
    const float m1  = exML[slot];
    const float l1v = exML[128 + slot];
    const float mm = fmaxf(m, m1);
    const float c0 = __builtin_amdgcn_exp2f(m - mm);
    const float c1 = __builtin_amdgcn_exp2f(m1 - mm);
    const float inv = 1.f / (l * c0 + l1v * c1);
    __bf16* yrow = y + ((size_t)(b * S_LEN + q)) * EMB + h * DH;
    #pragma unroll
    for (int d2 = 0; d2 < 2; d2++)
      #pragma unroll
      for (int rq = 0; rq < 4; rq++) {
        bf16x4 o4;
        #pragma unroll
        for (int jj = 0; jj < 4; jj++) {
          const int r = rq * 4 + jj;
          float v = (o_acc[d2][r] * c0 + exO[(d2 * 16 + r) * 128 + slot] * c1) * inv;
          o4[jj] = (__bf16)v;
        }
        // d = d2*32 + rq*8 + hl*4 + jj
        *(bf16x4*)&yrow[d2 * 32 + rq * 8 + hl * 4] = o4;
      }
  }
}

// ---------------- Launch ----------------
extern "C" void kernel_launch(void* const* d_in, const int* in_sizes, int n_in,
                              void* d_out, int out_size, void* d_ws, size_t ws_size,
                              hipStream_t stream) {
  const float* x      = (const float*)d_in[0];  // (B, S, E)
  const float* w_attn = (const float*)d_in[1];  // (E, 3E)
  const float* w_proj = (const float*)d_in[2];  // (E, E)
  float* out = (float*)d_out;                   // (B, S, E)

  const int B = in_sizes[0] / (S_LEN * EMB);    // = 2
  const int M = B * S_LEN;                      // 4096

  // bf16 workspace layout
  __bf16* xb   = (__bf16*)d_ws;                       // M x E          (8 MB)
  __bf16* wat  = xb  + (size_t)M * EMB;               // 3E x E transp  (6 MB)
  __bf16* wpt  = wat + (size_t)QKV_LD * EMB;          // E x E transp   (2 MB)
  __bf16* qkvb = wpt + (size_t)EMB * EMB;             // M x 3E         (24 MB)
  __bf16* yb   = qkvb + (size_t)M * QKV_LD;           // M x E          (8 MB)

  // 0) fused prep: cast + both weight transposes in one launch
  {
    int n8 = (M * EMB) / 8;   // 524288 -> 2048 cast blocks
    prep_fused<<<dim3(3072), 256, 0, stream>>>(x, xb, w_attn, wat, w_proj, wpt, n8);
  }

  // 1) qkv = x @ w_attn  (bf16 out, TN=128: grid 768 = 3 blocks/CU)
  dim3 g1(QKV_LD / 128, M / TM);
  gemm_bf16_mfma<__bf16, 128><<<g1, 256, 0, stream>>>(xb, wat, qkvb, M, QKV_LD, EMB);

  // 2) y = causal_attention(qkv)  [v19: KB=128, no split, no merge]
  attn_mfma<<<dim3(32 * NH * B), 256, 0, stream>>>(qkvb, yb);

  // 3) out = y @ w_proj  (f32 out, TN=64: grid 512 = 2 blocks/CU)
  dim3 g3(EMB / 64, M / TM);
  gemm_bf16_mfma<float, 64><<<g3, 256, 0, stream>>>(yb, wpt, out, M, EMB, EMB);
}

// Round 7
// 110.697 us; speedup vs baseline: 1.4725x; 1.4725x over previous
//
#include <hip/hip_runtime.h>
#include <hip/hip_bf16.h>

// Problem constants (B=2, S=2048, E=1024, H=16, Dh=64)
#define S_LEN 2048
#define EMB   1024
#define NH    16
#define DH    64
#define QKV_LD 3072   // 3*EMB

typedef __attribute__((ext_vector_type(8)))  __bf16 bf16x8;
typedef __attribute__((ext_vector_type(4)))  __bf16 bf16x4;
typedef __attribute__((ext_vector_type(4)))  float  f32x4;
typedef __attribute__((ext_vector_type(16))) float  f32x16;
typedef __attribute__((ext_vector_type(2)))  unsigned int u32x2;

// ---- async global->LDS (16B per lane; LDS dst = wave-uniform base) ----
__device__ __forceinline__ void gl_lds16(const void* g, void* l) {
  __builtin_amdgcn_global_load_lds(
      (const __attribute__((address_space(1))) void*)g,
      (__attribute__((address_space(3))) void*)l,
      16, 0, 0);
}

// ---------------- fused prep: cast x -> bf16, transpose+cast both weights --
__global__ __launch_bounds__(256)
void prep_fused(const float* __restrict__ x, __bf16* __restrict__ xb,
                const float* __restrict__ w_attn, __bf16* __restrict__ wat,
                const float* __restrict__ w_proj, __bf16* __restrict__ wpt,
                int n8) {
  __shared__ float T[64][65];
  const int bid = blockIdx.x;
  const int tid = threadIdx.x;

  if (bid < 2048) {
    int i = bid * 256 + tid;
    if (i >= n8) return;
    const f32x4* p = (const f32x4*)(x + (size_t)i * 8);
    f32x4 a = p[0], b = p[1];
    bf16x8 o;
    #pragma unroll
    for (int j = 0; j < 4; j++) { o[j] = (__bf16)a[j]; o[4 + j] = (__bf16)b[j]; }
    *(bf16x8*)(xb + (size_t)i * 8) = o;
    return;
  }

  const float* W; __bf16* Wt; int K, N, k0, n0;
  if (bid < 2048 + 768) {
    int t = bid - 2048;                 // w_attn: N=3072 -> 48 x-tiles, 16 k-tiles
    W = w_attn; Wt = wat; K = 1024; N = 3072;
    n0 = (t % 48) * 64; k0 = (t / 48) * 64;
  } else {
    int t = bid - 2816;                 // w_proj: 16 x 16 tiles
    W = w_proj; Wt = wpt; K = 1024; N = 1024;
    n0 = (t & 15) * 64; k0 = (t >> 4) * 64;
  }
  #pragma unroll
  for (int t = 0; t < 16; t++) {
    int idx = tid + t * 256;
    int r = idx >> 6, c = idx & 63;
    T[r][c] = W[(size_t)(k0 + r) * N + n0 + c];
  }
  __syncthreads();
  #pragma unroll
  for (int t = 0; t < 16; t++) {
    int idx = tid + t * 256;
    int r = idx >> 6, c = idx & 63;     // r = local n, c = local k
    Wt[(size_t)(n0 + r) * K + k0 + c] = (__bf16)T[c][r];
  }
}

// ---------------- bf16 MFMA GEMM: C(MxN) = A(MxK) @ Bt(NxK)^T -------------
#define TM 128
#define TK 32

template <typename OutT, int TNv>
__global__ __launch_bounds__(256, 2)
void gemm_bf16_mfma(const __bf16* __restrict__ A, const __bf16* __restrict__ Bt,
                    OutT* __restrict__ C, int M, int N, int K) {
  __shared__ __align__(16) __bf16 As[2][TM][TK];
  __shared__ __align__(16) __bf16 Bs[2][TNv][TK];
  const int tid  = threadIdx.x;
  const int lane = tid & 63;
  const int w    = tid >> 6;
  const int wr   = w >> 1, wc = w & 1;
  const int brow = blockIdx.y * TM;
  const int bcol = blockIdx.x * TNv;
  const int l15  = lane & 15;
  const int grp  = lane >> 4;

  constexpr int NBI = TNv / 64;        // B staging issues per wave
  constexpr int WCT = TNv / 2;         // wave column tile
  constexpr int NN  = WCT / 16;        // n-fragments per wave

  auto stage = [&](int k0, int buf) {
    #pragma unroll
    for (int j = 0; j < 2; j++) {       // A: 128x32 = 512 chunks, 2/wave
      const int cid = w * 128 + j * 64 + lane;
      const int row = cid >> 2, k8 = (cid & 3) * 8;
      gl_lds16(A + (size_t)(brow + row) * K + k0 + k8,
               &As[buf][0][0] + (size_t)(w * 128 + j * 64) * 8);
    }
    #pragma unroll
    for (int j = 0; j < NBI; j++) {     // B: TNv x 32 chunks
      const int cid = (w * NBI + j) * 64 + lane;
      const int row = cid >> 2, k8 = (cid & 3) * 8;
      gl_lds16(Bt + (size_t)(bcol + row) * K + k0 + k8,
               &Bs[buf][0][0] + (size_t)((w * NBI + j) * 64) * 8);
    }
  };

  f32x4 acc[4][NN];
  #pragma unroll
  for (int m = 0; m < 4; m++)
    #pragma unroll
    for (int n = 0; n < NN; n++) acc[m][n] = (f32x4){0.f, 0.f, 0.f, 0.f};

  stage(0, 0);
  __syncthreads();                      // drains prologue vmcnt

  const int nk = K / TK;
  for (int kt = 0; kt < nk; kt++) {
    const int cur = kt & 1;
    if (kt + 1 < nk) stage((kt + 1) * TK, cur ^ 1);   // prefetch under MFMA

    bf16x8 a[4], b[NN];
    #pragma unroll
    for (int m = 0; m < 4; m++)
      a[m] = *(const bf16x8*)&As[cur][wr * 64 + m * 16 + l15][grp * 8];
    #pragma unroll
    for (int n = 0; n < NN; n++)
      b[n] = *(const bf16x8*)&Bs[cur][wc * WCT + n * 16 + l15][grp * 8];
    #pragma unroll
    for (int m = 0; m < 4; m++)
      #pragma unroll
      for (int n = 0; n < NN; n++)
        acc[m][n] = __builtin_amdgcn_mfma_f32_16x16x32_bf16(a[m], b[n], acc[m][n], 0, 0, 0);

    __syncthreads();   // all waves done reading cur; prefetch landed
  }

  #pragma unroll
  for (int m = 0; m < 4; m++)
    #pragma unroll
    for (int r = 0; r < 4; r++) {
      const size_t row = (size_t)(brow + wr * 64 + m * 16 + grp * 4 + r);
      #pragma unroll
      for (int n = 0; n < NN; n++)
        C[row * N + bcol + wc * WCT + n * 16 + l15] = (OutT)acc[m][n][r];
    }
}

// ---------------- MFMA flash attention v20: KB=128, spill-free ------------
// v19 post-mortem: identical kernel at __launch_bounds__(256,4) spilled
// (live set ~140+ VGPR > 128 cap): FETCH 73MB / WRITE 52MB = scratch
// traffic, MfmaUtil 6.7%, 106us.  v20 = v19 with the cap lifted to
// (256,2) (256 VGPR budget): registers limit residency to 2 blocks/CU,
// which R2-R5 showed is occupancy-sufficient.  This is the clean test of
// the fat-iteration hypothesis: 34 iters/CU paying the fixed per-iteration
// overhead (X-wait + 3 barriers + reductions) half as often as KB=64.
#define QB 64
#define KB 128
#define QSCALE 0.18033688f   // 0.125 * log2(e)

__global__ __launch_bounds__(256, 2)
void attn_mfma(const __bf16* __restrict__ qkv, __bf16* __restrict__ y) {
  // 33792 B: Ks [128][64] bf16 (16KB) | Vs 2x8KB (16KB) | exML 1KB
  __shared__ __align__(16) char SMEM[33792];

  const int tid  = threadIdx.x;
  const int lane = tid & 63;
  const int w    = tid >> 6;

  // XCD-grouping swizzle + zigzag work balance (v13's decode, 1024 blocks)
  const int bid = blockIdx.x;                 // 0..1023
  const int swz = (bid & 7) * 128 + (bid >> 3);
  const int g   = swz >> 5;                   // (b,h) group 0..31
  const int i   = swz & 31;
  const int zig = (i & 1) ? (i >> 1) : 31 - (i >> 1);
  const int qtile = (g & 1) ? 31 - zig : zig;
  const int h = g & 15, b = g >> 4;

  const __bf16* base = qkv + (size_t)b * S_LEN * QKV_LD;

  const int l31 = lane & 31;
  const int hl  = lane >> 5;          // lane half (0/1)
  const int qh  = w >> 1;             // q-half of the 64-row tile
  const int kh  = w & 1;              // key-half (64 keys each) of the 128-tile

  // tr_read per-lane base inside wave's V sub-buffer (chunk bit in offsets)
  const int voff32 = ((lane >> 4) & 1) * 2048 + hl * 128 + (lane & 15) * 8;

  auto stageK = [&](int j0) {
    #pragma unroll
    for (int jj = 0; jj < 4; jj++) {
      const int cid = w * 256 + jj * 64 + lane;    // chunk 0..1023
      const int r = cid >> 3, pc = cid & 7;        // r = key row 0..127
      const int lc = pc ^ (r & 7);                 // inverse swizzle on source
      gl_lds16(base + (size_t)(j0 + r) * QKV_LD + EMB + h * DH + lc * 8,
               SMEM + cid * 16);
    }
  };
  auto stageV = [&](int j0) {
    #pragma unroll
    for (int jj = 0; jj < 4; jj++) {
      const int cid = w * 256 + jj * 64 + lane;    // chunk 0..1023
      const int c  = cid >> 9;                     // key-half sub-buffer
      const int cc = cid & 511;                    // old 8KB law inside
      const int db = cc >> 7, sk = (cc >> 3) & 15;
      const int jr = (cc >> 1) & 3, ch = cc & 1;
      gl_lds16(base + (size_t)(j0 + c * 64 + sk * 4 + jr) * QKV_LD + 2 * EMB
                    + h * DH + db * 16 + ch * 8,
               SMEM + 16384 + cid * 16);
    }
  };

  const int qbase = qtile * QB;
  const int q = qbase + qh * 32 + l31;           // this lane's q row

  // Q B-fragments (col=q, k_hw=d): qf[dq][i] = Q[q][dq*16 + hl*8 + i]
  bf16x8 qf[4];
  {
    const __bf16* qp = base + (size_t)q * QKV_LD + h * DH;
    #pragma unroll
    for (int dq = 0; dq < 4; dq++) {
      bf16x8 v = *(const bf16x8*)(qp + dq * 16 + hl * 8);
      #pragma unroll
      for (int i2 = 0; i2 < 8; i2++) qf[dq][i2] = (__bf16)((float)v[i2] * QSCALE);
    }
  }

  f32x16 o_acc[2];
  #pragma unroll
  for (int d2 = 0; d2 < 2; d2++)
    #pragma unroll
    for (int r = 0; r < 16; r++) o_acc[d2][r] = 0.f;
  float m = -1e30f, l = 0.f;

  const int krow0 = kh * 64 + l31;     // chunk 0 K-row; chunk 1 = +32
  const int ksw   = l31 & 7;           // swizzle key (same for both chunks)

  auto iter = [&](int j0, bool masked, int jn, bool do_stage) {
    asm volatile("s_waitcnt vmcnt(0)" ::: "memory");
    __builtin_amdgcn_s_barrier();                      // X: K,V of tile landed
    __builtin_amdgcn_sched_barrier(0);

    // ---- S^T = K Q: two 32k x 32q chunks, chained over d ----
    f32x16 s0, s1;
    #pragma unroll
    for (int r = 0; r < 16; r++) { s0[r] = 0.f; s1[r] = 0.f; }
    __builtin_amdgcn_s_setprio(1);
    #pragma unroll
    for (int dq = 0; dq < 4; dq++) {
      const int col = ((dq * 2 + hl) ^ ksw) * 16;
      bf16x8 kf0 = *(const bf16x8*)(SMEM + krow0 * 128 + col);
      bf16x8 kf1 = *(const bf16x8*)(SMEM + (krow0 + 32) * 128 + col);
      s0 = __builtin_amdgcn_mfma_f32_32x32x16_bf16(kf0, qf[dq], s0, 0, 0, 0);
      s1 = __builtin_amdgcn_mfma_f32_32x32x16_bf16(kf1, qf[dq], s1, 0, 0, 0);
    }
    __builtin_amdgcn_s_setprio(0);

    if (masked) {
      const int lim0 = q - j0 - kh * 64 - 4 * hl;  // keep if kl <= lim
      #pragma unroll
      for (int r = 0; r < 16; r++) {
        const int kl = (r & 3) + 8 * (r >> 2);
        if (kl > lim0)      s0[r] = -2e30f;
        if (kl > lim0 - 32) s1[r] = -2e30f;
      }
    }

    // ---- issue all 16 V^T transpose reads (latency under max tree) ----
    const unsigned vb =
        (unsigned)(uintptr_t)(__attribute__((address_space(3))) char*)
            (SMEM + 16384) + (unsigned)(kh * 8192 + voff32);
    u32x2 tv0[8], tv1[8];
    asm volatile("ds_read_b64_tr_b16 %0, %1 offset:0"    : "=v"(tv0[0]) : "v"(vb));
    asm volatile("ds_read_b64_tr_b16 %0, %1 offset:256"  : "=v"(tv0[1]) : "v"(vb));
    asm volatile("ds_read_b64_tr_b16 %0, %1 offset:512"  : "=v"(tv0[2]) : "v"(vb));
    asm volatile("ds_read_b64_tr_b16 %0, %1 offset:768"  : "=v"(tv0[3]) : "v"(vb));
    asm volatile("ds_read_b64_tr_b16 %0, %1 offset:4096" : "=v"(tv0[4]) : "v"(vb));
    asm volatile("ds_read_b64_tr_b16 %0, %1 offset:4352" : "=v"(tv0[5]) : "v"(vb));
    asm volatile("ds_read_b64_tr_b16 %0, %1 offset:4608" : "=v"(tv0[6]) : "v"(vb));
    asm volatile("ds_read_b64_tr_b16 %0, %1 offset:4864" : "=v"(tv0[7]) : "v"(vb));
    asm volatile("ds_read_b64_tr_b16 %0, %1 offset:1024" : "=v"(tv1[0]) : "v"(vb));
    asm volatile("ds_read_b64_tr_b16 %0, %1 offset:1280" : "=v"(tv1[1]) : "v"(vb));
    asm volatile("ds_read_b64_tr_b16 %0, %1 offset:1536" : "=v"(tv1[2]) : "v"(vb));
    asm volatile("ds_read_b64_tr_b16 %0, %1 offset:1792" : "=v"(tv1[3]) : "v"(vb));
    asm volatile("ds_read_b64_tr_b16 %0, %1 offset:5120" : "=v"(tv1[4]) : "v"(vb));
    asm volatile("ds_read_b64_tr_b16 %0, %1 offset:5376" : "=v"(tv1[5]) : "v"(vb));
    asm volatile("ds_read_b64_tr_b16 %0, %1 offset:5632" : "=v"(tv1[6]) : "v"(vb));
    asm volatile("ds_read_b64_tr_b16 %0, %1 offset:5888" : "=v"(tv1[7]) : "v"(vb));

    // ---- max reduce: pairwise + depth-4 tree + ONE cross-half shuffle ----
    float x0 = fmaxf(fmaxf(s0[0], s1[0]),  fmaxf(s0[8],  s1[8]));
    float x1 = fmaxf(fmaxf(s0[1], s1[1]),  fmaxf(s0[9],  s1[9]));
    float x2 = fmaxf(fmaxf(s0[2], s1[2]),  fmaxf(s0[10], s1[10]));
    float x3 = fmaxf(fmaxf(s0[3], s1[3]),  fmaxf(s0[11], s1[11]));
    float x4 = fmaxf(fmaxf(s0[4], s1[4]),  fmaxf(s0[12], s1[12]));
    float x5 = fmaxf(fmaxf(s0[5], s1[5]),  fmaxf(s0[13], s1[13]));
    float x6 = fmaxf(fmaxf(s0[6], s1[6]),  fmaxf(s0[14], s1[14]));
    float x7 = fmaxf(fmaxf(s0[7], s1[7]),  fmaxf(s0[15], s1[15]));
    x0 = fmaxf(x0, x4); x1 = fmaxf(x1, x5);
    x2 = fmaxf(x2, x6); x3 = fmaxf(x3, x7);
    float tmax = fmaxf(fmaxf(x0, x2), fmaxf(x1, x3));
    tmax = fmaxf(tmax, __shfl_xor(tmax, 32));

    const bool grow = !__all(tmax <= m + 8.0f);
    float corr = 1.f;
    if (grow) {
      const float mnew = fmaxf(m, tmax);
      corr = __builtin_amdgcn_exp2f(m - mnew);
      m = mnew;
    }

    __builtin_amdgcn_s_barrier();                      // Z: all QK reads done
    if (do_stage) stageK(jn);                          // Ks dead -> overwrite

    asm volatile("s_waitcnt lgkmcnt(0)" ::: "memory"); // tr data in regs
    __builtin_amdgcn_sched_barrier(0);
    __builtin_amdgcn_s_barrier();                      // Y: all tr reads done
    if (do_stage) stageV(jn);                          // Vs dead -> overwrite

    // ---- chunk 0: exp2 + psum + pack (frees s0 before chunk 1) ----
    float ps0 = 0.f, ps1 = 0.f, ps2 = 0.f, ps3 = 0.f;
    bf16x8 pb00, pb01, pb10, pb11;
    #pragma unroll
    for (int r = 0; r < 16; r += 4) {
      float p0 = __builtin_amdgcn_exp2f(s0[r]     - m);
      float p1 = __builtin_amdgcn_exp2f(s0[r + 1] - m);
      float p2 = __builtin_amdgcn_exp2f(s0[r + 2] - m);
      float p3 = __builtin_amdgcn_exp2f(s0[r + 3] - m);
      ps0 += p0; ps1 += p1; ps2 += p2; ps3 += p3;
      if (r < 8) { pb00[r] = (__bf16)p0; pb00[r+1] = (__bf16)p1;
                   pb00[r+2] = (__bf16)p2; pb00[r+3] = (__bf16)p3; }
      else       { pb01[r-8] = (__bf16)p0; pb01[r-7] = (__bf16)p1;
                   pb01[r-6] = (__bf16)p2; pb01[r-5] = (__bf16)p3; }
    }
    // ---- chunk 1: exp2 + psum + pack ----
    #pragma unroll
    for (int r = 0; r < 16; r += 4) {
      float p0 = __builtin_amdgcn_exp2f(s1[r]     - m);
      float p1 = __builtin_amdgcn_exp2f(s1[r + 1] - m);
      float p2 = __builtin_amdgcn_exp2f(s1[r + 2] - m);
      float p3 = __builtin_amdgcn_exp2f(s1[r + 3] - m);
      ps0 += p0; ps1 += p1; ps2 += p2; ps3 += p3;
      if (r < 8) { pb10[r] = (__bf16)p0; pb10[r+1] = (__bf16)p1;
                   pb10[r+2] = (__bf16)p2; pb10[r+3] = (__bf16)p3; }
      else       { pb11[r-8] = (__bf16)p0; pb11[r-7] = (__bf16)p1;
                   pb11[r-6] = (__bf16)p2; pb11[r-5] = (__bf16)p3; }
    }
    float psum = (ps0 + ps1) + (ps2 + ps3);

    // ---- O-rescale must precede PV ----
    if (grow) {
      #pragma unroll
      for (int d2 = 0; d2 < 2; d2++)
        #pragma unroll
        for (int r = 0; r < 16; r++) o_acc[d2][r] *= corr;
    }

    // ---- 8 back-to-back PV MFMAs (tv already drained) ----
    __builtin_amdgcn_s_setprio(1);
    #pragma unroll
    for (int d2 = 0; d2 < 2; d2++) {
      bf16x8 a0, a1, a2, a3;
      ((u32x2*)&a0)[0] = tv0[d2 * 4 + 0]; ((u32x2*)&a0)[1] = tv0[d2 * 4 + 1];
      ((u32x2*)&a1)[0] = tv0[d2 * 4 + 2]; ((u32x2*)&a1)[1] = tv0[d2 * 4 + 3];
      ((u32x2*)&a2)[0] = tv1[d2 * 4 + 0]; ((u32x2*)&a2)[1] = tv1[d2 * 4 + 1];
      ((u32x2*)&a3)[0] = tv1[d2 * 4 + 2]; ((u32x2*)&a3)[1] = tv1[d2 * 4 + 3];
      o_acc[d2] = __builtin_amdgcn_mfma_f32_32x32x16_bf16(a0, pb00, o_acc[d2], 0, 0, 0);
      o_acc[d2] = __builtin_amdgcn_mfma_f32_32x32x16_bf16(a1, pb01, o_acc[d2], 0, 0, 0);
      o_acc[d2] = __builtin_amdgcn_mfma_f32_32x32x16_bf16(a2, pb10, o_acc[d2], 0, 0, 0);
      o_acc[d2] = __builtin_amdgcn_mfma_f32_32x32x16_bf16(a3, pb11, o_acc[d2], 0, 0, 0);
    }
    __builtin_amdgcn_s_setprio(0);

    // ---- l-update (off the PV critical path) ----
    psum += __shfl_xor(psum, 32);
    l = grow ? (l * corr + psum) : (l + psum);
  };

  // prologue: stage tile 0 (X-barrier of iteration 0 drains it)
  stageK(0);
  stageV(0);

  const int nt = (qtile + 2) >> 1;     // ceil((qtile+1)/2) 128-key tiles
  #pragma unroll 1
  for (int tt = 0; tt < nt; tt++) {
    iter(tt * KB, tt == nt - 1, (tt + 1) * KB, tt + 1 < nt);
  }

  // ---- kh-pair merge through LDS, then epilogue by kh=0 waves ----
  __syncthreads();     // all waves done; reuse SMEM as exchange space
  float* exO  = (float*)SMEM;               // [32 rows][128 slots] = 16 KB
  float* exML = (float*)(SMEM + 32768);     // [2][128] f32 = 1 KB
  const int slot = qh * 64 + lane;
  if (kh) {
    #pragma unroll
    for (int r = 0; r < 16; r++) {
      exO[r * 128 + slot]        = o_acc[0][r];
      exO[(16 + r) * 128 + slot] = o_acc[1][r];
    }
    exML[slot]       = m;
    exML[128 + slot] = l;
  }
  __syncthreads();
  if (!kh) {
    const float m1  = exML[slot];
    const float l1v = exML[128 + slot];
    const float mm = fmaxf(m, m1);
    const float c0 = __builtin_amdgcn_exp2f(m - mm);
    const float c1 = __builtin_amdgcn_exp2f(m1 - mm);
    const float inv = 1.f / (l * c0 + l1v * c1);
    __bf16* yrow = y + ((size_t)(b * S_LEN + q)) * EMB + h * DH;
    #pragma unroll
    for (int d2 = 0; d2 < 2; d2++)
      #pragma unroll
      for (int rq = 0; rq < 4; rq++) {
        bf16x4 o4;
        #pragma unroll
        for (int jj = 0; jj < 4; jj++) {
          const int r = rq * 4 + jj;
          float v = (o_acc[d2][r] * c0 + exO[(d2 * 16 + r) * 128 + slot] * c1) * inv;
          o4[jj] = (__bf16)v;
        }
        // d = d2*32 + rq*8 + hl*4 + jj
        *(bf16x4*)&yrow[d2 * 32 + rq * 8 + hl * 4] = o4;
      }
  }
}

// ---------------- Launch ----------------
extern "C" void kernel_launch(void* const* d_in, const int* in_sizes, int n_in,
                              void* d_out, int out_size, void* d_ws, size_t ws_size,
                              hipStream_t stream) {
  const float* x      = (const float*)d_in[0];  // (B, S, E)
  const float* w_attn = (const float*)d_in[1];  // (E, 3E)
  const float* w_proj = (const float*)d_in[2];  // (E, E)
  float* out = (float*)d_out;                   // (B, S, E)

  const int B = in_sizes[0] / (S_LEN * EMB);    // = 2
  const int M = B * S_LEN;                      // 4096

  // bf16 workspace layout
  __bf16* xb   = (__bf16*)d_ws;                       // M x E          (8 MB)
  __bf16* wat  = xb  + (size_t)M * EMB;               // 3E x E transp  (6 MB)
  __bf16* wpt  = wat + (size_t)QKV_LD * EMB;          // E x E transp   (2 MB)
  __bf16* qkvb = wpt + (size_t)EMB * EMB;             // M x 3E         (24 MB)
  __bf16* yb   = qkvb + (size_t)M * QKV_LD;           // M x E          (8 MB)

  // 0) fused prep: cast + both weight transposes in one launch
  {
    int n8 = (M * EMB) / 8;   // 524288 -> 2048 cast blocks
    prep_fused<<<dim3(3072), 256, 0, stream>>>(x, xb, w_attn, wat, w_proj, wpt, n8);
  }

  // 1) qkv = x @ w_attn  (bf16 out, TN=128: grid 768 = 3 blocks/CU)
  dim3 g1(QKV_LD / 128, M / TM);
  gemm_bf16_mfma<__bf16, 128><<<g1, 256, 0, stream>>>(xb, wat, qkvb, M, QKV_LD, EMB);

  // 2) y = causal_attention(qkv)  [v20: KB=128, launch_bounds(256,2)]
  attn_mfma<<<dim3(32 * NH * B), 256, 0, stream>>>(qkvb, yb);

  // 3) out = y @ w_proj  (f32 out, TN=64: grid 512 = 2 blocks/CU)
  dim3 g3(EMB / 64, M / TM);
  gemm_bf16_mfma<float, 64><<<g3, 256, 0, stream>>>(yb, wpt, out, M, EMB, EMB);
}